// Round 5
// baseline (5221.383 us; speedup 1.0000x reference)
//
#include <hip/hip_runtime.h>
#include <hip/hip_bf16.h>
#include <cstdint>
#include <cstddef>

// MemoryEfficientLinearAttention — round 4 submission.
// Rounds 0-4: GPUAcquisitionTimeout; kernel has NEVER executed.
// Green path: hand-verified fp32 pipeline (owns d_out, unchanged).
// Shadow: bf16-MFMA GEMM (m97 structure) -> dead v_ws, now WITH bias, plus a
// numerical-error side-channel: probe_diff_spin's dispatch DURATION encodes
// max|q_bf16 - q_fp32|:  diff ~= dur_us / 1e5  (clamped at 1000us; absent
// from top-5 => diff < ~1e-3). One green run = baseline counters + MFMA
// speed A/B + bf16 tolerance estimate.
// B=4, S=8192, E=1024, H=16, D=64, M=B*S=32768.

#define B_ 4
#define S_ 8192
#define E_ 1024
#define H_ 16
#define D_ 64
#define M_ (B_ * S_)  // 32768

typedef __attribute__((ext_vector_type(8))) short s16x8;
typedef __attribute__((ext_vector_type(4))) float f32x4_t;

// ---------------- GEMM: C[M][N] = X[M][K] @ W[N][K]^T + bias (fp32) --------
#define TM 128
#define TN 128
#define TK 16

__global__ __launch_bounds__(256) void gemm_xwT(
    const float* __restrict__ X, const float* __restrict__ W,
    const float* __restrict__ bias, float* __restrict__ C,
    int M, int N, int K)
{
  __shared__ float As[TK][TM + 4];
  __shared__ float Bs[TK][TN + 4];
  const int tid = threadIdx.x;
  const int m0 = blockIdx.y * TM;
  const int n0 = blockIdx.x * TN;
  const int tx = tid & 15;
  const int ty = tid >> 4;

  float acc[2][2][4][4] = {};

  const int lrow0 = tid >> 2;          // 0..63 (and +64)
  const int kq = (tid & 3) * 4;        // 0,4,8,12

  for (int kt = 0; kt < K; kt += TK) {
    #pragma unroll
    for (int i = 0; i < 2; ++i) {
      const int row = lrow0 + i * 64;
      const float4 a = *(const float4*)(X + (size_t)(m0 + row) * K + kt + kq);
      const float4 b = *(const float4*)(W + (size_t)(n0 + row) * K + kt + kq);
      As[kq + 0][row] = a.x; As[kq + 1][row] = a.y;
      As[kq + 2][row] = a.z; As[kq + 3][row] = a.w;
      Bs[kq + 0][row] = b.x; Bs[kq + 1][row] = b.y;
      Bs[kq + 2][row] = b.z; Bs[kq + 3][row] = b.w;
    }
    __syncthreads();
    #pragma unroll
    for (int kk = 0; kk < TK; ++kk) {
      float a[8], b[8];
      *(float4*)&a[0] = *(const float4*)&As[kk][ty * 4];
      *(float4*)&a[4] = *(const float4*)&As[kk][64 + ty * 4];
      *(float4*)&b[0] = *(const float4*)&Bs[kk][tx * 4];
      *(float4*)&b[4] = *(const float4*)&Bs[kk][64 + tx * 4];
      #pragma unroll
      for (int ri = 0; ri < 2; ++ri)
        #pragma unroll
        for (int i = 0; i < 4; ++i)
          #pragma unroll
          for (int ci = 0; ci < 2; ++ci)
            #pragma unroll
            for (int j = 0; j < 4; ++j)
              acc[ri][ci][i][j] = fmaf(a[ri * 4 + i], b[ci * 4 + j], acc[ri][ci][i][j]);
    }
    __syncthreads();
  }

  const float4 bl = *(const float4*)(bias + n0 + tx * 4);
  const float4 bh = *(const float4*)(bias + n0 + 64 + tx * 4);
  #pragma unroll
  for (int ri = 0; ri < 2; ++ri) {
    #pragma unroll
    for (int i = 0; i < 4; ++i) {
      const size_t row = (size_t)(m0 + ri * 64 + ty * 4 + i);
      float4 v0 = make_float4(acc[ri][0][i][0] + bl.x, acc[ri][0][i][1] + bl.y,
                              acc[ri][0][i][2] + bl.z, acc[ri][0][i][3] + bl.w);
      float4 v1 = make_float4(acc[ri][1][i][0] + bh.x, acc[ri][1][i][1] + bh.y,
                              acc[ri][1][i][2] + bh.z, acc[ri][1][i][3] + bh.w);
      *(float4*)(C + row * N + n0 + tx * 4) = v0;
      *(float4*)(C + row * N + n0 + 64 + tx * 4) = v1;
    }
  }
}

// ---------------- kv partial: per (b,h) per S-chunk ----------------
#define NCHUNK 16
#define CROWS (S_ / NCHUNK)  // 512
#define KVR 8

__global__ __launch_bounds__(256) void kv_partial(
    const float* __restrict__ Kf, const float* __restrict__ Vf,
    float* __restrict__ kv_part, float* __restrict__ ksum_part)
{
  const int chunk = blockIdx.x;
  const int bh = blockIdx.y;
  const int b = bh >> 4, h = bh & 15;
  const int tid = threadIdx.x;
  const int lane = tid & 63, wave = tid >> 6;
  const int tx = tid & 15, ty = tid >> 4;

  __shared__ float kl[KVR][64];
  __shared__ float vl[KVR][64];
  __shared__ float ksw[4][64];

  const size_t base = ((size_t)b * S_ + (size_t)chunk * CROWS) * E_ + h * D_;
  const float* kbase = Kf + base;
  const float* vbase = Vf + base;

  float acc[4][4] = {};
  float ksacc = 0.f;

  const int which = tid >> 7;        // 0 -> k, 1 -> v
  const int l2 = tid & 127;
  const int lr = l2 >> 4;            // 0..7
  const int lc = (l2 & 15) * 4;

  for (int s = 0; s < CROWS; s += KVR) {
    {
      const float* src = which ? vbase : kbase;
      float* dst = which ? &vl[lr][lc] : &kl[lr][lc];
      *(float4*)dst = *(const float4*)(src + (size_t)(s + lr) * E_ + lc);
    }
    __syncthreads();
    // exp(k - rowmax) in-place; each wave owns 2 rows
    #pragma unroll
    for (int rr = 0; rr < 2; ++rr) {
      const int r = wave * 2 + rr;
      const float kx = kl[r][lane];
      float mx = kx;
      #pragma unroll
      for (int off = 32; off >= 1; off >>= 1) mx = fmaxf(mx, __shfl_xor(mx, off, 64));
      const float e = expf(kx - mx);
      kl[r][lane] = e;
      ksacc += e;
    }
    __syncthreads();
    #pragma unroll
    for (int r = 0; r < KVR; ++r) {
      const float4 kd = *(const float4*)&kl[r][ty * 4];
      const float4 ve = *(const float4*)&vl[r][tx * 4];
      const float kda[4] = {kd.x, kd.y, kd.z, kd.w};
      const float vea[4] = {ve.x, ve.y, ve.z, ve.w};
      #pragma unroll
      for (int i = 0; i < 4; ++i)
        #pragma unroll
        for (int j = 0; j < 4; ++j)
          acc[i][j] = fmaf(kda[i], vea[j], acc[i][j]);
    }
    __syncthreads();
  }

  const size_t pbase = ((size_t)bh * NCHUNK + chunk) * (D_ * D_);
  #pragma unroll
  for (int i = 0; i < 4; ++i) {
    float4 o = make_float4(acc[i][0], acc[i][1], acc[i][2], acc[i][3]);
    *(float4*)(kv_part + pbase + (size_t)(ty * 4 + i) * D_ + tx * 4) = o;
  }
  ksw[wave][lane] = ksacc;
  __syncthreads();
  if (wave == 0) {
    const float s = ksw[0][lane] + ksw[1][lane] + ksw[2][lane] + ksw[3][lane];
    ksum_part[((size_t)bh * NCHUNK + chunk) * D_ + lane] = s;
  }
}

// ---------------- reduce partials ----------------
__global__ __launch_bounds__(256) void kv_reduce(
    const float* __restrict__ kv_part, const float* __restrict__ ksum_part,
    float* __restrict__ kv, float* __restrict__ ksum)
{
  const int bh = blockIdx.x;
  const int tid = threadIdx.x;
  #pragma unroll
  for (int i = 0; i < 16; ++i) {
    const int e = tid + i * 256;
    float s = 0.f;
    #pragma unroll
    for (int c = 0; c < NCHUNK; ++c)
      s += kv_part[((size_t)bh * NCHUNK + c) * 4096 + e];
    kv[(size_t)bh * 4096 + e] = s;
  }
  if (tid < 64) {
    float s = 0.f;
    #pragma unroll
    for (int c = 0; c < NCHUNK; ++c)
      s += ksum_part[((size_t)bh * NCHUNK + c) * 64 + tid];
    ksum[(size_t)bh * 64 + tid] = s;
  }
}

// ---------------- y = exp(q-rowmax)@kv / denom ----------------
__global__ __launch_bounds__(256) void y_kernel(
    const float* __restrict__ Qf, const float* __restrict__ kv,
    const float* __restrict__ ksum, float* __restrict__ Y)
{
  const int tile = blockIdx.x;   // 0..127 (64 rows each)
  const int bh = blockIdx.y;
  const int b = bh >> 4, h = bh & 15;
  const int tid = threadIdx.x;
  const int lane = tid & 63, wave = tid >> 6;
  const int tx = tid & 15, ty = tid >> 4;

  __shared__ float qT[64][65];     // [d][row], padded
  __shared__ float kvl[64][64];    // [d][e]
  __shared__ float ksl[64];
  __shared__ float dinv[64];

  #pragma unroll
  for (int i = 0; i < 4; ++i) {
    const int l = tid + i * 256;   // float4 index 0..1023
    *(float4*)&((float*)kvl)[4 * l] = *(const float4*)(kv + (size_t)bh * 4096 + 4 * l);
  }
  if (tid < 64) ksl[tid] = ksum[(size_t)bh * 64 + tid];
  __syncthreads();

  const float* qbase = Qf + ((size_t)b * S_ + (size_t)tile * 64) * E_ + h * D_;
  for (int rr = 0; rr < 16; ++rr) {
    const int r = wave * 16 + rr;
    const float q = qbase[(size_t)r * E_ + lane];
    float mx = q;
    #pragma unroll
    for (int off = 32; off >= 1; off >>= 1) mx = fmaxf(mx, __shfl_xor(mx, off, 64));
    const float e = expf(q - mx);
    qT[lane][r] = e;
    float dp = e * ksl[lane];
    #pragma unroll
    for (int off = 32; off >= 1; off >>= 1) dp += __shfl_xor(dp, off, 64);
    if (lane == 0) dinv[r] = 1.f / (dp + 1e-6f);
  }
  __syncthreads();

  float acc[4][4] = {};
  #pragma unroll 8
  for (int kk = 0; kk < 64; ++kk) {
    const float4 a = *(const float4*)&qT[kk][ty * 4];
    const float4 v = *(const float4*)&kvl[kk][tx * 4];
    const float aa[4] = {a.x, a.y, a.z, a.w};
    const float vv[4] = {v.x, v.y, v.z, v.w};
    #pragma unroll
    for (int i = 0; i < 4; ++i)
      #pragma unroll
      for (int j = 0; j < 4; ++j)
        acc[i][j] = fmaf(aa[i], vv[j], acc[i][j]);
  }

  float* ybase = Y + ((size_t)b * S_ + (size_t)tile * 64) * E_ + h * D_;
  #pragma unroll
  for (int i = 0; i < 4; ++i) {
    const int r = ty * 4 + i;
    const float sc = dinv[r];
    float4 o = make_float4(acc[i][0] * sc, acc[i][1] * sc,
                           acc[i][2] * sc, acc[i][3] * sc);
    *(float4*)(ybase + (size_t)r * E_ + tx * 4) = o;
  }
}

// ================= SHADOW: bf16 MFMA GEMM (m97 structure) + bias ===========
// Writes ONLY to dead workspace (v_ws). 128x128 tile, BK=64, global_load_lds
// width=16 (linear LDS), mfma_f32_16x16x32_bf16, 4 waves (2x2), 4x4 frags.

__device__ __forceinline__ void gload_lds16(const void* g, void* l) {
  __builtin_amdgcn_global_load_lds(
      (const __attribute__((address_space(1))) void*)g,
      (__attribute__((address_space(3))) void*)l, 16, 0, 0);
}

#define SBM 128
#define SBK 64

__global__ __launch_bounds__(256) void gemm_bf16_shadow(
    const __hip_bfloat16* __restrict__ Xb,   // [M][K] bf16
    const __hip_bfloat16* __restrict__ Wb,   // [N][K] bf16
    const float* __restrict__ bias,          // [N]
    float* __restrict__ C, int M, int N, int K)
{
  __shared__ __hip_bfloat16 Al[SBM * SBK];   // 16 KB, [row][k] linear
  __shared__ __hip_bfloat16 Bl[SBM * SBK];   // 16 KB
  const int tid = threadIdx.x;
  const int lane = tid & 63, w = tid >> 6;
  const int m0 = blockIdx.y * SBM, n0 = blockIdx.x * SBM;
  const int wr = w >> 1, wc = w & 1;
  const int srow = lane >> 3;          // 0..7 (row within 8-row chunk)
  const int scol = (lane & 7) * 8;     // 0..56 (k offset)
  const int fr = lane & 15, fq = lane >> 4;

  f32x4_t acc[4][4];
  #pragma unroll
  for (int i = 0; i < 4; ++i)
    #pragma unroll
    for (int j = 0; j < 4; ++j) acc[i][j] = (f32x4_t){0.f, 0.f, 0.f, 0.f};

  for (int kt = 0; kt < K; kt += SBK) {
    // stage A,B tiles: 16 chunks of 1KB each per operand, 4 per wave
    #pragma unroll
    for (int i = 0; i < 4; ++i) {
      const int c = w * 4 + i;                         // 0..15
      const int row = c * 8 + srow;                    // 0..127
      gload_lds16(Xb + (size_t)(m0 + row) * K + kt + scol, Al + c * 512);
      gload_lds16(Wb + (size_t)(n0 + row) * K + kt + scol, Bl + c * 512);
    }
    asm volatile("s_waitcnt vmcnt(0)" ::: "memory");
    __syncthreads();
    #pragma unroll
    for (int ks = 0; ks < 2; ++ks) {
      s16x8 a[4], b[4];
      #pragma unroll
      for (int mi = 0; mi < 4; ++mi)
        a[mi] = *(const s16x8*)(Al + (wr * 64 + mi * 16 + fr) * 64 + ks * 32 + fq * 8);
      #pragma unroll
      for (int ni = 0; ni < 4; ++ni)
        b[ni] = *(const s16x8*)(Bl + (wc * 64 + ni * 16 + fr) * 64 + ks * 32 + fq * 8);
      #pragma unroll
      for (int mi = 0; mi < 4; ++mi)
        #pragma unroll
        for (int ni = 0; ni < 4; ++ni)
          acc[mi][ni] = __builtin_amdgcn_mfma_f32_16x16x32_bf16(a[mi], b[ni], acc[mi][ni], 0, 0, 0);
    }
    __syncthreads();
  }

  // C/D layout (verified m89/m91): col = lane&15, row = (lane>>4)*4 + reg
  #pragma unroll
  for (int ni = 0; ni < 4; ++ni) {
    const int col = n0 + wc * 64 + ni * 16 + fr;
    const float bcol = bias[col];
    #pragma unroll
    for (int mi = 0; mi < 4; ++mi)
      #pragma unroll
      for (int r = 0; r < 4; ++r) {
        const int row = m0 + wr * 64 + mi * 16 + fq * 4 + r;
        C[(size_t)row * N + col] = acc[mi][ni][r] + bcol;
      }
  }
}

__global__ __launch_bounds__(256) void f32_to_bf16(
    const float* __restrict__ in, __hip_bfloat16* __restrict__ out, long n8)
{
  const long i = (long)blockIdx.x * 256 + threadIdx.x;
  if (i >= n8) return;
  const float4 lo = *(const float4*)(in + i * 8);
  const float4 hi = *(const float4*)(in + i * 8 + 4);
  __hip_bfloat16 tmp[8];
  tmp[0] = __float2bfloat16(lo.x); tmp[1] = __float2bfloat16(lo.y);
  tmp[2] = __float2bfloat16(lo.z); tmp[3] = __float2bfloat16(lo.w);
  tmp[4] = __float2bfloat16(hi.x); tmp[5] = __float2bfloat16(hi.y);
  tmp[6] = __float2bfloat16(hi.z); tmp[7] = __float2bfloat16(hi.w);
  *(s16x8*)(out + i * 8) = *(const s16x8*)tmp;
}

// ======== bf16-error side-channel: max|a-b| -> spin-duration encoding ======
__global__ void zero_scalar(float* p) { if (threadIdx.x == 0) p[0] = 0.f; }

__global__ __launch_bounds__(256) void diff_max(
    const float* __restrict__ a, const float* __restrict__ b,
    float* __restrict__ dmax, long n)
{
  const long i0 = (long)blockIdx.x * (256 * 16) + threadIdx.x;
  float m = 0.f;
  #pragma unroll
  for (int it = 0; it < 16; ++it) {
    const long i = i0 + (long)it * 256;
    if (i < n) m = fmaxf(m, fabsf(a[i] - b[i]));
  }
  #pragma unroll
  for (int off = 32; off >= 1; off >>= 1) m = fmaxf(m, __shfl_xor(m, off, 64));
  if ((threadIdx.x & 63) == 0)
    atomicMax((int*)dmax, __float_as_int(m));  // floats >= 0: int order == float order
}

// Dispatch duration (us) ~= min(1000, diff * 1e5); read diff = dur_us / 1e5.
__global__ void probe_diff_spin(const float* __restrict__ dmax) {
  if (threadIdx.x != 0) return;
  const float d = dmax[0];
  const double us = fmin(1000.0, (double)d * 1e5);
  if (us < 1.0) return;
  const long long ticks = (long long)(us * 100.0);  // s_memrealtime ~100 MHz
  const long long start = __builtin_amdgcn_s_memrealtime();
  while (__builtin_amdgcn_s_memrealtime() - start < ticks) {}
}

// ---------------- launch ----------------
extern "C" void kernel_launch(void* const* d_in, const int* in_sizes, int n_in,
                              void* d_out, int out_size, void* d_ws, size_t ws_size,
                              hipStream_t stream)
{
  (void)in_sizes; (void)n_in; (void)out_size;
  const float* x  = (const float*)d_in[0];
  const float* Wq = (const float*)d_in[1];
  const float* bq = (const float*)d_in[2];
  const float* Wk = (const float*)d_in[3];
  const float* bk = (const float*)d_in[4];
  const float* Wv = (const float*)d_in[5];
  const float* bv = (const float*)d_in[6];
  const float* Wo = (const float*)d_in[7];
  const float* bo = (const float*)d_in[8];
  float* out = (float*)d_out;

  const size_t MB4 = (size_t)M_ * E_;          // 33,554,432 elements
  float* q_ws     = (float*)d_ws;
  float* k_ws     = q_ws + MB4;
  float* v_ws     = k_ws + MB4;
  float* kv_part  = v_ws + MB4;                                  // 64*16*4096
  float* ksum_prt = kv_part + (size_t)64 * NCHUNK * 4096;        // 64*16*64
  float* kvb      = ksum_prt + (size_t)64 * NCHUNK * 64;         // 64*4096
  float* ksum     = kvb + (size_t)64 * 4096;                     // 64*64
  float* base_end = ksum + 64 * 64;
  float* y_ws     = k_ws;  // k dead after kv_reduce; reuse for y

  const dim3 gg(E_ / TN, M_ / TM);  // (8, 256)
  gemm_xwT<<<gg, 256, 0, stream>>>(x, Wq, bq, q_ws, M_, E_, E_);
  gemm_xwT<<<gg, 256, 0, stream>>>(x, Wk, bk, k_ws, M_, E_, E_);
  gemm_xwT<<<gg, 256, 0, stream>>>(x, Wv, bv, v_ws, M_, E_, E_);
  kv_partial<<<dim3(NCHUNK, 64), 256, 0, stream>>>(k_ws, v_ws, kv_part, ksum_prt);
  kv_reduce<<<dim3(64), 256, 0, stream>>>(kv_part, ksum_prt, kvb, ksum);
  y_kernel<<<dim3(S_ / 64, 64), 256, 0, stream>>>(q_ws, kvb, ksum, y_ws);
  gemm_xwT<<<gg, 256, 0, stream>>>(y_ws, Wo, bo, out, M_, E_, E_);

  // ---- shadow bf16 experiment + error probe (q_ws live, v_ws dead) ----
  const size_t base_bytes = (size_t)((char*)base_end - (char*)d_ws);
  const size_t xb_bytes = MB4 * sizeof(__hip_bfloat16);                 // 67.1 MB
  const size_t wb_bytes = (size_t)E_ * E_ * sizeof(__hip_bfloat16);     // 2.1 MB
  if (ws_size >= base_bytes + xb_bytes + wb_bytes + sizeof(float)) {
    __hip_bfloat16* xb = (__hip_bfloat16*)base_end;
    __hip_bfloat16* wb = (__hip_bfloat16*)((char*)xb + xb_bytes);
    float* dmax = (float*)((char*)wb + wb_bytes);
    f32_to_bf16<<<(int)(MB4 / 8 / 256), 256, 0, stream>>>(x, xb, (long)(MB4 / 8));
    f32_to_bf16<<<(int)((size_t)E_ * E_ / 8 / 256), 256, 0, stream>>>(Wq, wb, (long)((size_t)E_ * E_ / 8));
    // shadow q' = x@Wq^T + bq in bf16, into dead v_ws (twice: warm timing)
    gemm_bf16_shadow<<<dim3(E_ / SBM, M_ / SBM), 256, 0, stream>>>(xb, wb, bq, v_ws, M_, E_, E_);
    gemm_bf16_shadow<<<dim3(E_ / SBM, M_ / SBM), 256, 0, stream>>>(xb, wb, bq, v_ws, M_, E_, E_);
    // error side-channel: diff(q', q) -> spin whose duration encodes it
    zero_scalar<<<1, 64, 0, stream>>>(dmax);
    diff_max<<<(int)(MB4 / (256 * 16)), 256, 0, stream>>>(v_ws, q_ws, dmax, (long)MB4);
    probe_diff_spin<<<1, 64, 0, stream>>>(dmax);
  }
}

// Round 7
// 956.464 us; speedup vs baseline: 5.4590x; 5.4590x over previous
//
#include <hip/hip_runtime.h>
#include <hip/hip_bf16.h>
#include <cstdint>
#include <cstddef>

// MemoryEfficientLinearAttention — round 6 (resubmit of round-5 bf16 port;
// GPU unavailable again, port has never executed).
// R4 data: fp32 GEMMs = 4x970us (VALUBusy 76%, MfmaUtil 0) of 5221us total;
// absmax(fp32)=4.88e-4 passed. This version: all 4 GEMMs ->
// mfma_f32_16x16x32_bf16 (m97 structure, bias fused, XCD swizzle);
// q/k/v/y stored bf16; attention core fp32 in-register.
// B=4, S=8192, E=1024, H=16, D=64, M=B*S=32768.

#define B_ 4
#define S_ 8192
#define E_ 1024
#define H_ 16
#define D_ 64
#define M_ (B_ * S_)  // 32768

typedef __attribute__((ext_vector_type(8))) short s16x8;
typedef __attribute__((ext_vector_type(4))) short s16x4;
typedef __attribute__((ext_vector_type(4))) float f32x4_t;

__device__ __forceinline__ float bf2f(unsigned short u) {
  union { unsigned int i; float f; } c; c.i = ((unsigned int)u) << 16; return c.f;
}
__device__ __forceinline__ short f2bf(float f) {
  __hip_bfloat16 h = __float2bfloat16(f);
  return *reinterpret_cast<short*>(&h);
}

// ---------------- f32 -> bf16 bulk convert ----------------
__global__ __launch_bounds__(256) void f32_to_bf16(
    const float* __restrict__ in, unsigned short* __restrict__ out, long n8)
{
  const long i = (long)blockIdx.x * 256 + threadIdx.x;
  if (i >= n8) return;
  const float4 lo = *(const float4*)(in + i * 8);
  const float4 hi = *(const float4*)(in + i * 8 + 4);
  s16x8 v;
  v[0] = f2bf(lo.x); v[1] = f2bf(lo.y); v[2] = f2bf(lo.z); v[3] = f2bf(lo.w);
  v[4] = f2bf(hi.x); v[5] = f2bf(hi.y); v[6] = f2bf(hi.z); v[7] = f2bf(hi.w);
  *(s16x8*)(out + i * 8) = v;
}

// ---------------- bf16 MFMA GEMM: C = Xb @ Wb^T + bias ----------------
// 128x128 tile, BK=64, global_load_lds 16B, linear LDS, 4 waves (2x2),
// 4x4 16x16x32 fragments/wave. XCD-swizzled 1D grid (nwg % 8 == 0).
__device__ __forceinline__ void gload_lds16(const void* g, void* l) {
  __builtin_amdgcn_global_load_lds(
      (const __attribute__((address_space(1))) void*)g,
      (__attribute__((address_space(3))) void*)l, 16, 0, 0);
}

template <bool OUT_BF16>
__global__ __launch_bounds__(256) void gemm_bf16(
    const unsigned short* __restrict__ Xb,  // [M][K] bf16
    const unsigned short* __restrict__ Wb,  // [N][K] bf16
    const float* __restrict__ bias,         // [N]
    void* __restrict__ Cout,                // [M][N] bf16 or f32
    int M, int N, int K)
{
  __shared__ unsigned short Al[128 * 64];   // 16 KB row-major [row][k]
  __shared__ unsigned short Bl[128 * 64];
  const int tid = threadIdx.x;
  const int lane = tid & 63, w = tid >> 6;
  // XCD swizzle: each XCD gets a contiguous chunk of tile space (m157 form)
  const int nwg = gridDim.x;
  const int cpx = nwg >> 3;
  const int swz = (blockIdx.x & 7) * cpx + (blockIdx.x >> 3);
  const int ntx = N >> 7;                   // N/128
  const int m0 = (swz / ntx) << 7, n0 = (swz % ntx) << 7;
  const int wr = w >> 1, wc = w & 1;
  const int srow = lane >> 3;               // 0..7
  const int scol = (lane & 7) * 8;          // 0..56
  const int fr = lane & 15, fq = lane >> 4;

  f32x4_t acc[4][4];
  #pragma unroll
  for (int i = 0; i < 4; ++i)
    #pragma unroll
    for (int j = 0; j < 4; ++j) acc[i][j] = (f32x4_t){0.f, 0.f, 0.f, 0.f};

  for (int kt = 0; kt < K; kt += 64) {
    #pragma unroll
    for (int i = 0; i < 4; ++i) {
      const int c = w * 4 + i;              // 0..15 chunks of 8 rows
      const int row = c * 8 + srow;
      gload_lds16(Xb + (size_t)(m0 + row) * K + kt + scol, Al + c * 512);
      gload_lds16(Wb + (size_t)(n0 + row) * K + kt + scol, Bl + c * 512);
    }
    asm volatile("s_waitcnt vmcnt(0)" ::: "memory");
    __syncthreads();
    #pragma unroll
    for (int ks = 0; ks < 2; ++ks) {
      s16x8 a[4], b[4];
      #pragma unroll
      for (int mi = 0; mi < 4; ++mi)
        a[mi] = *(const s16x8*)(Al + (wr * 64 + mi * 16 + fr) * 64 + ks * 32 + fq * 8);
      #pragma unroll
      for (int ni = 0; ni < 4; ++ni)
        b[ni] = *(const s16x8*)(Bl + (wc * 64 + ni * 16 + fr) * 64 + ks * 32 + fq * 8);
      #pragma unroll
      for (int mi = 0; mi < 4; ++mi)
        #pragma unroll
        for (int ni = 0; ni < 4; ++ni)
          acc[mi][ni] = __builtin_amdgcn_mfma_f32_16x16x32_bf16(a[mi], b[ni], acc[mi][ni], 0, 0, 0);
    }
    __syncthreads();
  }

  // C/D layout (m89/m91): col = lane&15, row = (lane>>4)*4 + reg
  #pragma unroll
  for (int ni = 0; ni < 4; ++ni) {
    const int col = n0 + wc * 64 + ni * 16 + fr;
    const float bcol = bias[col];
    #pragma unroll
    for (int mi = 0; mi < 4; ++mi)
      #pragma unroll
      for (int r = 0; r < 4; ++r) {
        const int row = m0 + wr * 64 + mi * 16 + fq * 4 + r;
        const float v = acc[mi][ni][r] + bcol;
        if (OUT_BF16)
          ((unsigned short*)Cout)[(size_t)row * N + col] = (unsigned short)f2bf(v);
        else
          ((float*)Cout)[(size_t)row * N + col] = v;
      }
  }
}

// ---------------- kv partial: per (b,h) per S-chunk (bf16 in) --------------
#define NCHUNK 16
#define CROWS (S_ / NCHUNK)  // 512
#define KVR 8

__global__ __launch_bounds__(256) void kv_partial(
    const unsigned short* __restrict__ Kb, const unsigned short* __restrict__ Vb,
    float* __restrict__ kv_part, float* __restrict__ ksum_part)
{
  const int chunk = blockIdx.x;
  const int bh = blockIdx.y;
  const int b = bh >> 4, h = bh & 15;
  const int tid = threadIdx.x;
  const int lane = tid & 63, wave = tid >> 6;
  const int tx = tid & 15, ty = tid >> 4;

  __shared__ float kl[KVR][64];
  __shared__ float vl[KVR][64];
  __shared__ float ksw[4][64];

  const size_t base = ((size_t)b * S_ + (size_t)chunk * CROWS) * E_ + h * D_;
  const unsigned short* kbase = Kb + base;
  const unsigned short* vbase = Vb + base;

  float acc[4][4] = {};
  float ksacc = 0.f;

  const int which = tid >> 7;        // 0 -> k, 1 -> v
  const int l2 = tid & 127;
  const int lr = l2 >> 4;            // 0..7
  const int lc = (l2 & 15) * 4;      // 0..60

  for (int s = 0; s < CROWS; s += KVR) {
    {
      const unsigned short* src = which ? vbase : kbase;
      float* dst = which ? &vl[lr][lc] : &kl[lr][lc];
      const s16x4 raw = *(const s16x4*)(src + (size_t)(s + lr) * E_ + lc);
      dst[0] = bf2f((unsigned short)raw[0]);
      dst[1] = bf2f((unsigned short)raw[1]);
      dst[2] = bf2f((unsigned short)raw[2]);
      dst[3] = bf2f((unsigned short)raw[3]);
    }
    __syncthreads();
    // exp(k - rowmax) in-place; each wave owns 2 rows
    #pragma unroll
    for (int rr = 0; rr < 2; ++rr) {
      const int r = wave * 2 + rr;
      const float kx = kl[r][lane];
      float mx = kx;
      #pragma unroll
      for (int off = 32; off >= 1; off >>= 1) mx = fmaxf(mx, __shfl_xor(mx, off, 64));
      const float e = expf(kx - mx);
      kl[r][lane] = e;
      ksacc += e;
    }
    __syncthreads();
    #pragma unroll
    for (int r = 0; r < KVR; ++r) {
      const float4 kd = *(const float4*)&kl[r][ty * 4];
      const float4 ve = *(const float4*)&vl[r][tx * 4];
      const float kda[4] = {kd.x, kd.y, kd.z, kd.w};
      const float vea[4] = {ve.x, ve.y, ve.z, ve.w};
      #pragma unroll
      for (int i = 0; i < 4; ++i)
        #pragma unroll
        for (int j = 0; j < 4; ++j)
          acc[i][j] = fmaf(kda[i], vea[j], acc[i][j]);
    }
    __syncthreads();
  }

  const size_t pbase = ((size_t)bh * NCHUNK + chunk) * (D_ * D_);
  #pragma unroll
  for (int i = 0; i < 4; ++i) {
    float4 o = make_float4(acc[i][0], acc[i][1], acc[i][2], acc[i][3]);
    *(float4*)(kv_part + pbase + (size_t)(ty * 4 + i) * D_ + tx * 4) = o;
  }
  ksw[wave][lane] = ksacc;
  __syncthreads();
  if (wave == 0) {
    const float s = ksw[0][lane] + ksw[1][lane] + ksw[2][lane] + ksw[3][lane];
    ksum_part[((size_t)bh * NCHUNK + chunk) * D_ + lane] = s;
  }
}

// ---------------- reduce partials ----------------
__global__ __launch_bounds__(256) void kv_reduce(
    const float* __restrict__ kv_part, const float* __restrict__ ksum_part,
    float* __restrict__ kv, float* __restrict__ ksum)
{
  const int bh = blockIdx.x;
  const int tid = threadIdx.x;
  #pragma unroll
  for (int i = 0; i < 16; ++i) {
    const int e = tid + i * 256;
    float s = 0.f;
    #pragma unroll
    for (int c = 0; c < NCHUNK; ++c)
      s += kv_part[((size_t)bh * NCHUNK + c) * 4096 + e];
    kv[(size_t)bh * 4096 + e] = s;
  }
  if (tid < 64) {
    float s = 0.f;
    #pragma unroll
    for (int c = 0; c < NCHUNK; ++c)
      s += ksum_part[((size_t)bh * NCHUNK + c) * 64 + tid];
    ksum[(size_t)bh * 64 + tid] = s;
  }
}

// ---------------- y = exp(q-rowmax)@kv / denom  (bf16 in, bf16 out) --------
__global__ __launch_bounds__(256) void y_kernel(
    const unsigned short* __restrict__ Qb, const float* __restrict__ kv,
    const float* __restrict__ ksum, unsigned short* __restrict__ Yb)
{
  const int tile = blockIdx.x;   // 0..127 (64 rows each)
  const int bh = blockIdx.y;
  const int b = bh >> 4, h = bh & 15;
  const int tid = threadIdx.x;
  const int lane = tid & 63, wave = tid >> 6;
  const int tx = tid & 15, ty = tid >> 4;

  __shared__ float qT[64][65];     // [d][row], padded
  __shared__ float kvl[64][64];    // [d][e]
  __shared__ float ksl[64];
  __shared__ float dinv[64];

  #pragma unroll
  for (int i = 0; i < 4; ++i) {
    const int l = tid + i * 256;   // float4 index 0..1023
    *(float4*)&((float*)kvl)[4 * l] = *(const float4*)(kv + (size_t)bh * 4096 + 4 * l);
  }
  if (tid < 64) ksl[tid] = ksum[(size_t)bh * 64 + tid];
  __syncthreads();

  const unsigned short* qbase = Qb + ((size_t)b * S_ + (size_t)tile * 64) * E_ + h * D_;
  for (int rr = 0; rr < 16; ++rr) {
    const int r = wave * 16 + rr;
    const float q = bf2f(qbase[(size_t)r * E_ + lane]);
    float mx = q;
    #pragma unroll
    for (int off = 32; off >= 1; off >>= 1) mx = fmaxf(mx, __shfl_xor(mx, off, 64));
    const float e = expf(q - mx);
    qT[lane][r] = e;
    float dp = e * ksl[lane];
    #pragma unroll
    for (int off = 32; off >= 1; off >>= 1) dp += __shfl_xor(dp, off, 64);
    if (lane == 0) dinv[r] = 1.f / (dp + 1e-6f);
  }
  __syncthreads();

  float acc[4][4] = {};
  #pragma unroll 8
  for (int kk = 0; kk < 64; ++kk) {
    const float4 a = *(const float4*)&qT[kk][ty * 4];
    const float4 v = *(const float4*)&kvl[kk][tx * 4];
    const float aa[4] = {a.x, a.y, a.z, a.w};
    const float vv[4] = {v.x, v.y, v.z, v.w};
    #pragma unroll
    for (int i = 0; i < 4; ++i)
      #pragma unroll
      for (int j = 0; j < 4; ++j)
        acc[i][j] = fmaf(aa[i], vv[j], acc[i][j]);
  }

  unsigned short* ybase = Yb + ((size_t)b * S_ + (size_t)tile * 64) * E_ + h * D_;
  #pragma unroll
  for (int i = 0; i < 4; ++i) {
    const int r = ty * 4 + i;
    const float sc = dinv[r];
    s16x4 o;
    o[0] = f2bf(acc[i][0] * sc); o[1] = f2bf(acc[i][1] * sc);
    o[2] = f2bf(acc[i][2] * sc); o[3] = f2bf(acc[i][3] * sc);
    *(s16x4*)(ybase + (size_t)r * E_ + tx * 4) = o;
  }
}

// ---------------- launch ----------------
extern "C" void kernel_launch(void* const* d_in, const int* in_sizes, int n_in,
                              void* d_out, int out_size, void* d_ws, size_t ws_size,
                              hipStream_t stream)
{
  (void)in_sizes; (void)n_in; (void)out_size; (void)ws_size;
  const float* x  = (const float*)d_in[0];
  const float* Wq = (const float*)d_in[1];
  const float* bq = (const float*)d_in[2];
  const float* Wk = (const float*)d_in[3];
  const float* bk = (const float*)d_in[4];
  const float* Wv = (const float*)d_in[5];
  const float* bv = (const float*)d_in[6];
  const float* Wo = (const float*)d_in[7];
  const float* bo = (const float*)d_in[8];
  float* out = (float*)d_out;

  const size_t ME = (size_t)M_ * E_;          // 33,554,432
  const size_t EE = (size_t)E_ * E_;          // 1,048,576
  unsigned short* qb  = (unsigned short*)d_ws;           // bf16 q   (67MB)
  unsigned short* kb  = qb + ME;                         // bf16 k   (67MB)
  unsigned short* vb  = kb + ME;                         // bf16 v   (67MB)
  unsigned short* xb  = vb + ME;                         // bf16 x; later y (67MB)
  unsigned short* wqb = xb + ME;                         // bf16 weights 4x2MB
  unsigned short* wkb = wqb + EE;
  unsigned short* wvb = wkb + EE;
  unsigned short* wob = wvb + EE;
  float* kv_part  = (float*)(wob + EE);                  // 64*16*4096 (16.8MB)
  float* ksum_prt = kv_part + (size_t)64 * NCHUNK * 4096;
  float* kvb      = ksum_prt + (size_t)64 * NCHUNK * 64; // 64*4096
  float* ksum     = kvb + (size_t)64 * 4096;             // 64*64
  unsigned short* yb = xb;   // x dead after projections

  // converts
  f32_to_bf16<<<(int)(ME / 8 / 256), 256, 0, stream>>>(x, xb, (long)(ME / 8));
  f32_to_bf16<<<(int)(EE / 8 / 256), 256, 0, stream>>>(Wq, wqb, (long)(EE / 8));
  f32_to_bf16<<<(int)(EE / 8 / 256), 256, 0, stream>>>(Wk, wkb, (long)(EE / 8));
  f32_to_bf16<<<(int)(EE / 8 / 256), 256, 0, stream>>>(Wv, wvb, (long)(EE / 8));
  f32_to_bf16<<<(int)(EE / 8 / 256), 256, 0, stream>>>(Wo, wob, (long)(EE / 8));

  const int nwg = (M_ / 128) * (E_ / 128);    // 2048, % 8 == 0
  // projections (bf16 out)
  gemm_bf16<true><<<nwg, 256, 0, stream>>>(xb, wqb, bq, qb, M_, E_, E_);
  gemm_bf16<true><<<nwg, 256, 0, stream>>>(xb, wkb, bk, kb, M_, E_, E_);
  gemm_bf16<true><<<nwg, 256, 0, stream>>>(xb, wvb, bv, vb, M_, E_, E_);
  // attention core (fp32 math)
  kv_partial<<<dim3(NCHUNK, 64), 256, 0, stream>>>(kb, vb, kv_part, ksum_prt);
  kv_reduce<<<dim3(64), 256, 0, stream>>>(kv_part, ksum_prt, kvb, ksum);
  y_kernel<<<dim3(S_ / 64, 64), 256, 0, stream>>>(qb, kvb, ksum, yb);
  // output projection (f32 out -> d_out)
  gemm_bf16<false><<<nwg, 256, 0, stream>>>(yb, wob, bo, out, M_, E_, E_);
}

// Round 10
// 858.710 us; speedup vs baseline: 6.0805x; 1.1138x over previous
//
#include <hip/hip_runtime.h>
#include <hip/hip_bf16.h>
#include <cstdint>
#include <cstddef>

// MemoryEfficientLinearAttention — round 9 (resubmit of round-7 rewrite;
// GPU unavailable rounds 8-9; rewrite never executed; 4th audit clean).
// R6 green: 956us, absmax 4.88e-4. This version:
//  - exp(rowmax) hoisted into QKV-projection epilogue (butterfly over fr-lanes)
//  - QKV fused into one GEMM (N=3072), x staged once
//  - y via MFMA: A=qe natural layout, B=kvT preloaded in registers, denom via
//    in-register ksum dot + fq-butterfly; no LDS, no serial loop
//  - kv_core: 64-row staging (16 barriers vs 192), no exp, ksum piggyback
// B=4, S=8192, E=1024, H=16, D=64, M=B*S=32768.

#define B_ 4
#define S_ 8192
#define E_ 1024
#define H_ 16
#define D_ 64
#define M_ (B_ * S_)  // 32768

typedef __attribute__((ext_vector_type(8))) short s16x8;
typedef __attribute__((ext_vector_type(4))) short s16x4;
typedef __attribute__((ext_vector_type(4))) float f32x4_t;

__device__ __forceinline__ float bf2f(unsigned short u) {
  union { unsigned int i; float f; } c; c.i = ((unsigned int)u) << 16; return c.f;
}
__device__ __forceinline__ short f2bf(float f) {
  __hip_bfloat16 h = __float2bfloat16(f);
  return *reinterpret_cast<short*>(&h);
}

// ---------------- f32 -> bf16 bulk convert ----------------
__global__ __launch_bounds__(256) void f32_to_bf16(
    const float* __restrict__ in, unsigned short* __restrict__ out, long n8)
{
  const long i = (long)blockIdx.x * 256 + threadIdx.x;
  if (i >= n8) return;
  const float4 lo = *(const float4*)(in + i * 8);
  const float4 hi = *(const float4*)(in + i * 8 + 4);
  s16x8 v;
  v[0] = f2bf(lo.x); v[1] = f2bf(lo.y); v[2] = f2bf(lo.z); v[3] = f2bf(lo.w);
  v[4] = f2bf(hi.x); v[5] = f2bf(hi.y); v[6] = f2bf(hi.z); v[7] = f2bf(hi.w);
  *(s16x8*)(out + i * 8) = v;
}

__device__ __forceinline__ void gload_lds16(const void* g, void* l) {
  __builtin_amdgcn_global_load_lds(
      (const __attribute__((address_space(1))) void*)g,
      (__attribute__((address_space(3))) void*)l, 16, 0, 0);
}

// ============ fused QKV GEMM: [q|k|v] = xb @ wqkv^T + bias, exp on q/k ======
// N=3072. 128x128 tile, BK=64, global_load_lds, 4 waves (2x2), 4x4 frags.
// Epilogue: cols 0..1023 -> qe (exp per-head), 1024..2047 -> ke (exp),
// 2048..3071 -> vb (plain). All outputs bf16 [M][1024].
__global__ __launch_bounds__(256) void gemm_qkv(
    const unsigned short* __restrict__ Xb,    // [M][1024]
    const unsigned short* __restrict__ Wcat,  // [3072][1024]
    const float* __restrict__ bq, const float* __restrict__ bk,
    const float* __restrict__ bv,
    unsigned short* __restrict__ qe, unsigned short* __restrict__ ke,
    unsigned short* __restrict__ vb)
{
  const int K = E_, N = 3 * E_;
  __shared__ unsigned short Al[128 * 64];
  __shared__ unsigned short Bl[128 * 64];
  const int tid = threadIdx.x;
  const int lane = tid & 63, w = tid >> 6;
  const int nwg = gridDim.x;                 // 6144, %8==0
  const int cpx = nwg >> 3;
  const int swz = (blockIdx.x & 7) * cpx + (blockIdx.x >> 3);
  const int ntx = N >> 7;                    // 24
  const int m0 = (swz / ntx) << 7, n0 = (swz % ntx) << 7;
  const int wr = w >> 1, wc = w & 1;
  const int srow = lane >> 3;
  const int scol = (lane & 7) * 8;
  const int fr = lane & 15, fq = lane >> 4;

  f32x4_t acc[4][4];
  #pragma unroll
  for (int i = 0; i < 4; ++i)
    #pragma unroll
    for (int j = 0; j < 4; ++j) acc[i][j] = (f32x4_t){0.f, 0.f, 0.f, 0.f};

  for (int kt = 0; kt < K; kt += 64) {
    #pragma unroll
    for (int i = 0; i < 4; ++i) {
      const int c = w * 4 + i;
      const int row = c * 8 + srow;
      gload_lds16(Xb + (size_t)(m0 + row) * K + kt + scol, Al + c * 512);
      gload_lds16(Wcat + (size_t)(n0 + row) * K + kt + scol, Bl + c * 512);
    }
    asm volatile("s_waitcnt vmcnt(0)" ::: "memory");
    __syncthreads();
    #pragma unroll
    for (int ks = 0; ks < 2; ++ks) {
      s16x8 a[4], b[4];
      #pragma unroll
      for (int mi = 0; mi < 4; ++mi)
        a[mi] = *(const s16x8*)(Al + (wr * 64 + mi * 16 + fr) * 64 + ks * 32 + fq * 8);
      #pragma unroll
      for (int ni = 0; ni < 4; ++ni)
        b[ni] = *(const s16x8*)(Bl + (wc * 64 + ni * 16 + fr) * 64 + ks * 32 + fq * 8);
      #pragma unroll
      for (int mi = 0; mi < 4; ++mi)
        #pragma unroll
        for (int ni = 0; ni < 4; ++ni)
          acc[mi][ni] = __builtin_amdgcn_mfma_f32_16x16x32_bf16(a[mi], b[ni], acc[mi][ni], 0, 0, 0);
    }
    __syncthreads();
  }

  // --- epilogue ---
  // wave's 64 cols: c0 = n0 + wc*64 .. +63 — exactly one head of one matrix.
  const int c0 = n0 + wc * 64;
  const int id = c0 >> 10;                  // 0=q, 1=k, 2=v
  const int lc0 = c0 & 1023;                // head_base + 0
  const float* bias = (id == 0) ? bq : (id == 1) ? bk : bv;
  unsigned short* outp = (id == 0) ? qe : (id == 1) ? ke : vb;

  // add bias first (needed before max)
  float val[4][4][4];                        // [mi][ni][r]
  #pragma unroll
  for (int ni = 0; ni < 4; ++ni) {
    const float bcol = bias[lc0 + ni * 16 + fr];
    #pragma unroll
    for (int mi = 0; mi < 4; ++mi)
      #pragma unroll
      for (int r = 0; r < 4; ++r)
        val[mi][ni][r] = acc[mi][ni][r] + bcol;
  }

  if (id < 2) {
    // exp(v - rowmax) per head-row: rows indexed by (mi, fq, r).
    // max over ni (in-reg) then butterfly over the 16-lane fr group.
    #pragma unroll
    for (int mi = 0; mi < 4; ++mi)
      #pragma unroll
      for (int r = 0; r < 4; ++r) {
        float mx = fmaxf(fmaxf(val[mi][0][r], val[mi][1][r]),
                         fmaxf(val[mi][2][r], val[mi][3][r]));
        mx = fmaxf(mx, __shfl_xor(mx, 1));
        mx = fmaxf(mx, __shfl_xor(mx, 2));
        mx = fmaxf(mx, __shfl_xor(mx, 4));
        mx = fmaxf(mx, __shfl_xor(mx, 8));
        #pragma unroll
        for (int ni = 0; ni < 4; ++ni)
          val[mi][ni][r] = expf(val[mi][ni][r] - mx);
      }
  }

  #pragma unroll
  for (int ni = 0; ni < 4; ++ni) {
    const int col = lc0 + ni * 16 + fr;
    #pragma unroll
    for (int mi = 0; mi < 4; ++mi)
      #pragma unroll
      for (int r = 0; r < 4; ++r) {
        const int row = m0 + wr * 64 + mi * 16 + fq * 4 + r;
        outp[(size_t)row * E_ + col] = (unsigned short)f2bf(val[mi][ni][r]);
      }
  }
}

// ---------------- kv_core: kv[d][e] partials + ksum, per (b,h,chunk) -------
#define NCHUNK 16
#define CROWS (S_ / NCHUNK)  // 512

__global__ __launch_bounds__(256) void kv_core(
    const unsigned short* __restrict__ Ke, const unsigned short* __restrict__ Vb,
    float* __restrict__ kv_part, float* __restrict__ ksum_part)
{
  const int chunk = blockIdx.x;
  const int bh = blockIdx.y;
  const int b = bh >> 4, h = bh & 15;
  const int tid = threadIdx.x;
  const int tx = tid & 15, ty = tid >> 4;

  __shared__ float kst[64][64];   // [s][d] fp32
  __shared__ float vst[64][64];   // [s][e] fp32

  const size_t rbase = ((size_t)b * S_ + (size_t)chunk * CROWS);

  float acc[4][4] = {};
  float ksacc[4] = {0.f, 0.f, 0.f, 0.f};

  const int lrow = tid >> 2;          // 0..63
  const int lcq = (tid & 3) * 16;     // 0,16,32,48

  for (int it = 0; it < CROWS / 64; ++it) {   // 8 iterations
    {
      const size_t g = (rbase + it * 64 + lrow) * E_ + h * D_ + lcq;
      const s16x8 k0 = *(const s16x8*)(Ke + g);
      const s16x8 k1 = *(const s16x8*)(Ke + g + 8);
      const s16x8 v0 = *(const s16x8*)(Vb + g);
      const s16x8 v1 = *(const s16x8*)(Vb + g + 8);
      #pragma unroll
      for (int j = 0; j < 8; ++j) {
        kst[lrow][lcq + j] = bf2f((unsigned short)k0[j]);
        kst[lrow][lcq + 8 + j] = bf2f((unsigned short)k1[j]);
        vst[lrow][lcq + j] = bf2f((unsigned short)v0[j]);
        vst[lrow][lcq + 8 + j] = bf2f((unsigned short)v1[j]);
      }
    }
    __syncthreads();
    #pragma unroll 8
    for (int s = 0; s < 64; ++s) {
      const float4 kd = *(const float4*)&kst[s][ty * 4];
      const float4 ve = *(const float4*)&vst[s][tx * 4];
      const float kda[4] = {kd.x, kd.y, kd.z, kd.w};
      const float vea[4] = {ve.x, ve.y, ve.z, ve.w};
      #pragma unroll
      for (int i = 0; i < 4; ++i)
        #pragma unroll
        for (int j = 0; j < 4; ++j)
          acc[i][j] = fmaf(kda[i], vea[j], acc[i][j]);
      if (tx == 0) {
        #pragma unroll
        for (int i = 0; i < 4; ++i) ksacc[i] += kda[i];
      }
    }
    __syncthreads();
  }

  const size_t pbase = ((size_t)bh * NCHUNK + chunk) * (D_ * D_);
  #pragma unroll
  for (int i = 0; i < 4; ++i) {
    float4 o = make_float4(acc[i][0], acc[i][1], acc[i][2], acc[i][3]);
    *(float4*)(kv_part + pbase + (size_t)(ty * 4 + i) * D_ + tx * 4) = o;
  }
  if (tx == 0) {
    #pragma unroll
    for (int i = 0; i < 4; ++i)
      ksum_part[((size_t)bh * NCHUNK + chunk) * D_ + ty * 4 + i] = ksacc[i];
  }
}

// ---------------- reduce partials -> kvT bf16 + ksum f32 ----------------
__global__ __launch_bounds__(256) void kv_reduce(
    const float* __restrict__ kv_part, const float* __restrict__ ksum_part,
    unsigned short* __restrict__ kvT, float* __restrict__ ksum)
{
  const int bh = blockIdx.x;
  const int tid = threadIdx.x;
  #pragma unroll
  for (int i = 0; i < 16; ++i) {
    const int l = tid + i * 256;       // 0..4095
    const int d = l >> 6, e = l & 63;
    float s = 0.f;
    #pragma unroll
    for (int c = 0; c < NCHUNK; ++c)
      s += kv_part[((size_t)bh * NCHUNK + c) * 4096 + l];
    kvT[(size_t)bh * 4096 + e * 64 + d] = (unsigned short)f2bf(s);
  }
  if (tid < 64) {
    float s = 0.f;
    #pragma unroll
    for (int c = 0; c < NCHUNK; ++c)
      s += ksum_part[((size_t)bh * NCHUNK + c) * 64 + tid];
    ksum[(size_t)bh * 64 + tid] = s;
  }
}

// ---------------- y via MFMA: y = qe @ kvT^T / (qe.ksum + 1e-6) ------------
// Per wave: 16 q-rows. A = qe rows (natural [s][d] bf16), B = kvT [e][d]
// preloaded to 8 register fragments. No LDS.
__global__ __launch_bounds__(256) void y_mfma(
    const unsigned short* __restrict__ Qe, const unsigned short* __restrict__ kvT,
    const float* __restrict__ ksum, unsigned short* __restrict__ Yb)
{
  const int tile = blockIdx.x;    // 0..127 (64 rows per block)
  const int bh = blockIdx.y;
  const int b = bh >> 4, h = bh & 15;
  const int tid = threadIdx.x;
  const int lane = tid & 63, w = tid >> 6;
  const int fr = lane & 15, fq = lane >> 4;

  // B fragments: b[ni][ks] = kvT[bh][ni*16+fr][ks*32 + fq*8 ..+8]
  s16x8 bf[4][2];
  const unsigned short* kvb = kvT + (size_t)bh * 4096;
  #pragma unroll
  for (int ni = 0; ni < 4; ++ni)
    #pragma unroll
    for (int ks = 0; ks < 2; ++ks)
      bf[ni][ks] = *(const s16x8*)(kvb + (ni * 16 + fr) * 64 + ks * 32 + fq * 8);

  // ksum for this lane's two d-chunks: [fq*8..+8] and [32+fq*8..+8]
  float ks0[8], ks1[8];
  {
    const float* kp = ksum + (size_t)bh * 64;
    *(float4*)&ks0[0] = *(const float4*)(kp + fq * 8);
    *(float4*)&ks0[4] = *(const float4*)(kp + fq * 8 + 4);
    *(float4*)&ks1[0] = *(const float4*)(kp + 32 + fq * 8);
    *(float4*)&ks1[4] = *(const float4*)(kp + 32 + fq * 8 + 4);
  }

  // A fragments: this wave's rows = tile*64 + w*16 + fr
  const size_t srow = (size_t)b * S_ + (size_t)tile * 64 + w * 16 + fr;
  const unsigned short* qrow = Qe + srow * E_ + h * D_;
  const s16x8 a0 = *(const s16x8*)(qrow + fq * 8);
  const s16x8 a1 = *(const s16x8*)(qrow + 32 + fq * 8);

  // denom = qe_row . ksum  (partial over this lane's 16 d's, butterfly over fq)
  float dp = 0.f;
  #pragma unroll
  for (int j = 0; j < 8; ++j) {
    dp = fmaf(bf2f((unsigned short)a0[j]), ks0[j], dp);
    dp = fmaf(bf2f((unsigned short)a1[j]), ks1[j], dp);
  }
  dp += __shfl_xor(dp, 16);
  dp += __shfl_xor(dp, 32);
  const float dinv = 1.f / (dp + 1e-6f);   // lane L holds denom of row (L&15)

  // MFMA over d
  f32x4_t acc[4];
  #pragma unroll
  for (int ni = 0; ni < 4; ++ni) {
    acc[ni] = (f32x4_t){0.f, 0.f, 0.f, 0.f};
    acc[ni] = __builtin_amdgcn_mfma_f32_16x16x32_bf16(a0, bf[ni][0], acc[ni], 0, 0, 0);
    acc[ni] = __builtin_amdgcn_mfma_f32_16x16x32_bf16(a1, bf[ni][1], acc[ni], 0, 0, 0);
  }

  // C/D: col = ni*16 + fr (e), row = fq*4 + r (local) -> scale by that row's dinv
  unsigned short* ybase = Yb + ((size_t)b * S_ + (size_t)tile * 64 + w * 16) * E_ + h * D_;
  #pragma unroll
  for (int r = 0; r < 4; ++r) {
    const int lrow = fq * 4 + r;
    const float di = __shfl(dinv, lrow);   // lane lrow holds row lrow's dinv
    #pragma unroll
    for (int ni = 0; ni < 4; ++ni)
      ybase[(size_t)lrow * E_ + ni * 16 + fr] = (unsigned short)f2bf(acc[ni][r] * di);
  }
}

// ---------------- plain bf16 GEMM (O-projection): f32 out ----------------
__global__ __launch_bounds__(256) void gemm_o(
    const unsigned short* __restrict__ Xb,  // [M][K] bf16 (y)
    const unsigned short* __restrict__ Wb,  // [N][K] bf16 (Wo)
    const float* __restrict__ bias,
    float* __restrict__ C, int M, int N, int K)
{
  __shared__ unsigned short Al[128 * 64];
  __shared__ unsigned short Bl[128 * 64];
  const int tid = threadIdx.x;
  const int lane = tid & 63, w = tid >> 6;
  const int nwg = gridDim.x;
  const int cpx = nwg >> 3;
  const int swz = (blockIdx.x & 7) * cpx + (blockIdx.x >> 3);
  const int ntx = N >> 7;
  const int m0 = (swz / ntx) << 7, n0 = (swz % ntx) << 7;
  const int wr = w >> 1, wc = w & 1;
  const int srow = lane >> 3;
  const int scol = (lane & 7) * 8;
  const int fr = lane & 15, fq = lane >> 4;

  f32x4_t acc[4][4];
  #pragma unroll
  for (int i = 0; i < 4; ++i)
    #pragma unroll
    for (int j = 0; j < 4; ++j) acc[i][j] = (f32x4_t){0.f, 0.f, 0.f, 0.f};

  for (int kt = 0; kt < K; kt += 64) {
    #pragma unroll
    for (int i = 0; i < 4; ++i) {
      const int c = w * 4 + i;
      const int row = c * 8 + srow;
      gload_lds16(Xb + (size_t)(m0 + row) * K + kt + scol, Al + c * 512);
      gload_lds16(Wb + (size_t)(n0 + row) * K + kt + scol, Bl + c * 512);
    }
    asm volatile("s_waitcnt vmcnt(0)" ::: "memory");
    __syncthreads();
    #pragma unroll
    for (int ks = 0; ks < 2; ++ks) {
      s16x8 a[4], b[4];
      #pragma unroll
      for (int mi = 0; mi < 4; ++mi)
        a[mi] = *(const s16x8*)(Al + (wr * 64 + mi * 16 + fr) * 64 + ks * 32 + fq * 8);
      #pragma unroll
      for (int ni = 0; ni < 4; ++ni)
        b[ni] = *(const s16x8*)(Bl + (wc * 64 + ni * 16 + fr) * 64 + ks * 32 + fq * 8);
      #pragma unroll
      for (int mi = 0; mi < 4; ++mi)
        #pragma unroll
        for (int ni = 0; ni < 4; ++ni)
          acc[mi][ni] = __builtin_amdgcn_mfma_f32_16x16x32_bf16(a[mi], b[ni], acc[mi][ni], 0, 0, 0);
    }
    __syncthreads();
  }

  #pragma unroll
  for (int ni = 0; ni < 4; ++ni) {
    const int col = n0 + wc * 64 + ni * 16 + fr;
    const float bcol = bias[col];
    #pragma unroll
    for (int mi = 0; mi < 4; ++mi)
      #pragma unroll
      for (int r = 0; r < 4; ++r) {
        const int row = m0 + wr * 64 + mi * 16 + fq * 4 + r;
        C[(size_t)row * N + col] = acc[mi][ni][r] + bcol;
      }
  }
}

// ---------------- launch ----------------
extern "C" void kernel_launch(void* const* d_in, const int* in_sizes, int n_in,
                              void* d_out, int out_size, void* d_ws, size_t ws_size,
                              hipStream_t stream)
{
  (void)in_sizes; (void)n_in; (void)out_size; (void)ws_size;
  const float* x  = (const float*)d_in[0];
  const float* Wq = (const float*)d_in[1];
  const float* bq = (const float*)d_in[2];
  const float* Wk = (const float*)d_in[3];
  const float* bk = (const float*)d_in[4];
  const float* Wv = (const float*)d_in[5];
  const float* bv = (const float*)d_in[6];
  const float* Wo = (const float*)d_in[7];
  const float* bo = (const float*)d_in[8];
  float* out = (float*)d_out;

  const size_t ME = (size_t)M_ * E_;          // 33,554,432
  const size_t EE = (size_t)E_ * E_;          // 1,048,576
  unsigned short* xb   = (unsigned short*)d_ws;            // bf16 x      67MB
  unsigned short* qe   = xb + ME;                          // exp'd q     67MB
  unsigned short* ke   = qe + ME;                          // exp'd k     67MB
  unsigned short* vb   = ke + ME;                          // v bf16      67MB
  unsigned short* wqkv = vb + ME;                          // [3072][1024] 6.3MB
  unsigned short* wob  = wqkv + 3 * EE;                    // 2.1MB
  float* kv_part  = (float*)(wob + EE);                    // 16.8MB
  float* ksum_prt = kv_part + (size_t)64 * NCHUNK * 4096;
  unsigned short* kvT = (unsigned short*)(ksum_prt + (size_t)64 * NCHUNK * 64);
  float* ksum = (float*)(kvT + (size_t)64 * 4096);
  unsigned short* yb = ke;   // ke dead after kv_core; reuse for y

  // converts
  f32_to_bf16<<<(int)(ME / 8 / 256), 256, 0, stream>>>(x, xb, (long)(ME / 8));
  f32_to_bf16<<<(int)(EE / 8 / 256), 256, 0, stream>>>(Wq, wqkv, (long)(EE / 8));
  f32_to_bf16<<<(int)(EE / 8 / 256), 256, 0, stream>>>(Wk, wqkv + EE, (long)(EE / 8));
  f32_to_bf16<<<(int)(EE / 8 / 256), 256, 0, stream>>>(Wv, wqkv + 2 * EE, (long)(EE / 8));
  f32_to_bf16<<<(int)(EE / 8 / 256), 256, 0, stream>>>(Wo, wob, (long)(EE / 8));

  // fused QKV projection + exp epilogue
  gemm_qkv<<<(M_ / 128) * (3 * E_ / 128), 256, 0, stream>>>(
      xb, wqkv, bq, bk, bv, qe, ke, vb);
  // attention core
  kv_core<<<dim3(NCHUNK, 64), 256, 0, stream>>>(ke, vb, kv_part, ksum_prt);
  kv_reduce<<<dim3(64), 256, 0, stream>>>(kv_part, ksum_prt, kvT, ksum);
  y_mfma<<<dim3(S_ / 64, 64), 256, 0, stream>>>(qe, kvT, ksum, yb);
  // output projection
  gemm_o<<<(M_ / 128) * (E_ / 128), 256, 0, stream>>>(yb, wob, bo, out, M_, E_, E_);
}